// Round 2
// baseline (425.483 us; speedup 1.0000x reference)
//
#include <hip/hip_runtime.h>
#include <hip/hip_bf16.h>

// B=8, T=512, N=64, E=128, H=256, P=96.  bn = b*64+n (512 rows).
// Identities:
//  xe = x_noD*emb  => rfft factorizes: spectral scalar s[bn,k] (packed: k<=256 real, k>256 imag)
//  mlp(s*emb) piecewise-linear in s (257 regions; tables Atab/Btab[r][e])
//  xt-part of flat@fw1:  h2[bn,h] = sum_{k,e} Yp[bn,k,e] * M2[k,e,h],
//      M2[k,(h,e)] = sum_t W[t,k] fw1[(t*128+e)*256+h]   (W = packed irfft basis)
//  xn-part:   xn@F1s = hl@(tw2@F1s) + tb2@F1s,  F1s[t,h] = sum_e fw1
//  bias-part: x_noD@F1e,                        F1e[t,h] = sum_e (1+emb_e) fw1
//  F1s/F1e accumulated inside the fw1 transpose. s and x@F1e computed via
//  hi/lo bf16 K-concat MFMA (A=[hi|lo|hi], B=[hi;hi;lo]) => ~f32 exact.

typedef unsigned int uint;
typedef unsigned short ushort_t;
typedef __attribute__((ext_vector_type(4))) float f32x4;
typedef __attribute__((ext_vector_type(8))) short short8;

#define LAMBDA_ 0.001f
#define RSQRT512 0.044194173824159220f

__device__ __forceinline__ ushort_t f2bf(float f) {
    uint u = __float_as_uint(f);
    uint r = (u + 0x7FFFu + ((u >> 16) & 1u)) >> 16;
    return (ushort_t)r;
}
__device__ __forceinline__ float bf2f(ushort_t v) { return __uint_as_float(((uint)v) << 16); }
__device__ __forceinline__ float leaky_(float v) { return v >= 0.f ? v : 0.01f * v; }

// ---------------- K0: transpose x [8][512][64] -> A1cat [512 bn][1536] (hi|lo|hi) ----------------
__global__ __launch_bounds__(256) void k_transpose_x(const float* __restrict__ x, ushort_t* __restrict__ A1cat) {
    __shared__ float tile[32][33];
    int bid = blockIdx.x;             // 8 * 16 * 2 = 256
    int b = bid >> 5;
    int rem = bid & 31;
    int t0 = (rem >> 1) << 5;
    int n0 = (rem & 1) << 5;
    int tx = threadIdx.x & 31, ty = threadIdx.x >> 5;
    for (int i = 0; i < 4; ++i) {
        int tt = ty * 4 + i;
        tile[tt][tx] = x[(size_t)(b * 512 + t0 + tt) * 64 + n0 + tx];
    }
    __syncthreads();
    for (int i = 0; i < 4; ++i) {
        int nn = ty * 4 + i;
        float v = tile[tx][nn];
        ushort_t hi = f2bf(v);
        ushort_t lo = f2bf(v - bf2f(hi));
        size_t row = (size_t)(b * 64 + n0 + nn) * 1536;
        int t = t0 + tx;
        A1cat[row + t] = hi;
        A1cat[row + 512 + t] = lo;
        A1cat[row + 1024 + t] = hi;
    }
}

// ---------------- K1: setup — B1cat DFT rows, Wt, tw2_bf ----------------
// B1cat[n][c] (n<512: n=k): c<512 t=c: hi(D[t,k]); 512..1023: hi; >=1024: lo
// D[t,k] = cos(2pi t k/512)/sq for k<=256 ; -sin(2pi t (k-256)/512)/sq for k>256
// Wt[k][t] = irfft basis (scale 2 except k=0,256)
__global__ __launch_bounds__(256) void k_setup(const float* __restrict__ tw2,
                                               ushort_t* __restrict__ B1cat, ushort_t* __restrict__ Wt,
                                               ushort_t* __restrict__ tw2_bf) {
    int bid = blockIdx.x;
    int region = bid >> 10;
    int id = ((bid & 1023) << 8) + threadIdx.x;
    int a = id >> 9, c = id & 511;
    if (region == 0) {       // B1cat rows 0-511: D[t=c][k=a]
        int f = (a <= 256) ? a : (a - 256);
        int m = (c * f) & 511;
        float ang = (float)m * (6.283185307179586f / 512.0f);
        float v = ((a <= 256) ? cosf(ang) : -sinf(ang)) * RSQRT512;
        ushort_t hi = f2bf(v);
        ushort_t lo = f2bf(v - bf2f(hi));
        size_t row = (size_t)a * 1536;
        B1cat[row + c] = hi;
        B1cat[row + 512 + c] = hi;
        B1cat[row + 1024 + c] = lo;
    } else if (region == 1) {  // Wt[k=a][t=c]
        int f = (a <= 256) ? a : (a - 256);
        int m = (c * f) & 511;
        float ang = (float)m * (6.283185307179586f / 512.0f);
        float v = ((a <= 256) ? cosf(ang) : -sinf(ang)) * RSQRT512;
        float sc = (a == 0 || a == 256) ? 1.0f : 2.0f;
        Wt[id] = f2bf(v * sc);
    } else {                   // tw2_bf: 512 blocks used
        if ((bid & 1023) < 512) tw2_bf[id] = f2bf(tw2[id]);
    }
}

// ---------------- K2: pack tw1 -> B1cat rows 512-767 (transposed, hi|hi|lo) ----------------
__global__ __launch_bounds__(256) void k_pack_tw1(const float* __restrict__ tw1, ushort_t* __restrict__ B1cat) {
    __shared__ float tile[64][65];
    int bid = blockIdx.x;            // 8 t-tiles * 4 h-tiles = 32
    int t0 = (bid & 7) << 6, h0 = (bid >> 3) << 6;
    int tid = threadIdx.x;
    for (int i = 0; i < 16; ++i) {
        int idx = tid + i * 256;
        int r = idx >> 6, cc = idx & 63;
        tile[r][cc] = tw1[(size_t)(t0 + r) * 256 + h0 + cc];
    }
    __syncthreads();
    for (int i = 0; i < 16; ++i) {
        int idx = tid + i * 256;
        int rr = idx >> 6, cc2 = idx & 63;      // rr: h, cc2: t
        float v = tile[cc2][rr];
        ushort_t hi = f2bf(v);
        ushort_t lo = f2bf(v - bf2f(hi));
        size_t row = (size_t)(512 + h0 + rr) * 1536;
        int t = t0 + cc2;
        B1cat[row + t] = hi;
        B1cat[row + 512 + t] = hi;
        B1cat[row + 1024 + t] = lo;
    }
}

// ---------------- K3: piecewise-linear tables (1 block) -> bf16 Atab/Btab [257][128], bpkey ----------------
__global__ __launch_bounds__(256) void k_prep(const float* __restrict__ emb, const float* __restrict__ w1,
                                              const float* __restrict__ b1, const float* __restrict__ w2,
                                              const float* __restrict__ b2,
                                              ushort_t* __restrict__ Atab, ushort_t* __restrict__ Btab,
                                              float* __restrict__ bpkey_g) {
    __shared__ float u_s[256], b1_s[256], key_s[256];
    __shared__ int idx_s[256];
    int tid = threadIdx.x;
    float acc = 0.f;
    for (int e = 0; e < 128; ++e) acc += emb[e] * w1[e * 256 + tid];
    u_s[tid] = acc;
    float bb0 = b1[tid];
    b1_s[tid] = bb0;
    key_s[tid] = (acc == 0.f) ? INFINITY : (-bb0 / acc);
    idx_s[tid] = tid;
    __syncthreads();
    for (int k = 2; k <= 256; k <<= 1) {
        for (int j = k >> 1; j > 0; j >>= 1) {
            int ixj = tid ^ j;
            if (ixj > tid) {
                bool up = ((tid & k) == 0);
                float a0 = key_s[tid], a1 = key_s[ixj];
                if ((a0 > a1) == up) {
                    key_s[tid] = a1; key_s[ixj] = a0;
                    int t0 = idx_s[tid]; idx_s[tid] = idx_s[ixj]; idx_s[ixj] = t0;
                }
            }
            __syncthreads();
        }
    }
    bpkey_g[tid] = key_s[tid];
    if (tid < 128) {
        int e = tid;
        float aA = 0.f, aB = 0.f;
        for (int h = 0; h < 256; ++h) {
            float uu = u_s[h], bbh = b1_s[h];
            float c = (uu < 0.f || (uu == 0.f && bbh >= 0.f)) ? 1.0f : 0.01f;
            float w = w2[h * 128 + e];
            aA += c * uu * w;
            aB += c * bbh * w;
        }
        aB += b2[e];
        Atab[e] = f2bf(aA);
        Btab[e] = f2bf(aB);
        for (int r = 1; r <= 256; ++r) {
            int h = idx_s[r - 1];
            float uu = u_s[h], bbh = b1_s[h];
            float w = w2[h * 128 + e];
            float sgn = (uu > 0.f) ? 0.99f : -0.99f;
            aA += sgn * uu * w;
            aB += sgn * bbh * w;
            Atab[r * 128 + e] = f2bf(aA);
            Btab[r * 128 + e] = f2bf(aB);
        }
    }
}

// ---------------- K4: transpose fw1 -> fw1T[(h*128+e)][t] bf16, + accumulate F1sT/F1eT [h][t] f32 ----------------
__global__ __launch_bounds__(256) void k_transpose_fw1(const float* __restrict__ fw1, const float* __restrict__ emb,
                                                       ushort_t* __restrict__ fw1T,
                                                       float* __restrict__ F1sT, float* __restrict__ F1eT) {
    __shared__ float tile[64][65];
    int bid = blockIdx.x;                 // 8 tt * 4 hh * 8 g = 256
    int t0 = (bid & 7) << 6;
    int h0 = ((bid >> 3) & 3) << 6;
    int e0 = (bid >> 5) << 4;
    int tid = threadIdx.x;
    int rbase = tid >> 6, cc = tid & 63;
    float acc_s[16], acc_e[16];
    for (int i = 0; i < 16; ++i) { acc_s[i] = 0.f; acc_e[i] = 0.f; }
    for (int ei = 0; ei < 16; ++ei) {
        int e = e0 + ei;
        float w = 1.f + emb[e];
        __syncthreads();
        for (int i = 0; i < 16; ++i) {
            int r = i * 4 + rbase;
            float v = fw1[(size_t)(t0 + r) * 32768 + (size_t)e * 256 + h0 + cc];
            tile[r][cc] = v;
            acc_s[i] += v;
            acc_e[i] += w * v;
        }
        __syncthreads();
        for (int i = 0; i < 16; ++i) {
            int idx = tid + i * 256;
            int rr = idx >> 6, c2 = idx & 63;     // rr: h-offset, c2: t-offset
            fw1T[((size_t)((h0 + rr) * 128 + e)) * 512 + t0 + c2] = f2bf(tile[c2][rr]);
        }
    }
    for (int i = 0; i < 16; ++i) {
        int r = i * 4 + rbase;
        size_t dst = (size_t)(h0 + cc) * 512 + t0 + r;
        atomicAdd(F1sT + dst, acc_s[i]);
        atomicAdd(F1eT + dst, acc_e[i]);
    }
}

// ---------------- K5: pack F1s/F1e: B1cat rows 768-1023 (F1e hi|hi|lo), F1sT_bf, p2v = tb2@F1s ----------------
__global__ __launch_bounds__(64) void k_pack_F(const float* __restrict__ F1sT, const float* __restrict__ F1eT,
                                               const float* __restrict__ tb2,
                                               ushort_t* __restrict__ B1cat, ushort_t* __restrict__ F1sT_bf,
                                               float* __restrict__ p2v) {
    int h = blockIdx.x;                   // 256
    int lane = threadIdx.x;
    int t = lane * 8;
    float p2 = 0.f;
    short8 shi, ehi, elo;
    for (int j = 0; j < 8; ++j) {
        float vs = F1sT[(size_t)h * 512 + t + j];
        float ve = F1eT[(size_t)h * 512 + t + j];
        p2 += tb2[t + j] * vs;
        shi[j] = (short)f2bf(vs);
        ushort_t hi = f2bf(ve);
        ehi[j] = (short)hi;
        elo[j] = (short)f2bf(ve - bf2f(hi));
    }
    *(short8*)(F1sT_bf + (size_t)h * 512 + t) = shi;
    size_t row = (size_t)(768 + h) * 1536;
    *(short8*)(B1cat + row + t) = ehi;
    *(short8*)(B1cat + row + 512 + t) = ehi;
    *(short8*)(B1cat + row + 1024 + t) = elo;
    for (int o = 32; o > 0; o >>= 1) p2 += __shfl_xor(p2, o);
    if (lane == 0) p2v[h] = p2;
}

// ---------------- generic 128x128-tile bf16 MFMA GEMM; A [M][K] lda, B [N][K] ldb ----------------
// EPI 0: M2T scatter (GEMM0, custom XCD map, grid 1024)
// EPI 1: atomic f32 h2 (GEMM1, split-K custom XCD map, grid 256)
// EPI 2: G1: s f32 / hl bf16(leaky+tb1) / h2c f32 split by n  (grid 32)
// EPI 4: P2T transposed bf16 store (grid 4)
// EPI 5: h2b = acc + p2v[n] + h2c (grid 8)
template<int EPI>
__global__ __launch_bounds__(256) void k_mfma(const ushort_t* __restrict__ A, const ushort_t* __restrict__ Bm,
                                              int lda, int ldb, int kIters, int nTiles,
                                              void* __restrict__ C0, void* __restrict__ C1,
                                              void* __restrict__ C2, const float* __restrict__ aux) {
    __shared__ ushort_t As[128 * 72];
    __shared__ ushort_t Bs[128 * 72];
    int tid = threadIdx.x;
    int lane = tid & 63, wid = tid >> 6;
    int wr = wid >> 1, wc = wid & 1;
    int bid = blockIdx.x;
    int mt, nt, kc = 0;
    if (EPI == 1) {
        int xx = bid & 7, y = bid >> 3;
        kc = ((y & 3) << 3) | xx;
        int mem = y >> 2;
        mt = mem >> 1; nt = mem & 1;
    } else if (EPI == 0) {
        int xx = bid & 7, y = bid >> 3;
        mt = y & 3;
        nt = ((y >> 2) << 3) | xx;
    } else {
        nt = bid % nTiles;
        mt = bid / nTiles;
    }
    int m0 = mt * 128, n0 = nt * 128, k0 = kc * (kIters * 64);
    f32x4 acc[4][4] = {};
    for (int kt = 0; kt < kIters; ++kt) {
        int kb = k0 + kt * 64;
        __syncthreads();
        {
            uint4 va[4], vb[4];
            for (int i = 0; i < 4; ++i) {
                int q = tid + i * 256;
                int row = q >> 3, kcc = (q & 7) << 3;
                va[i] = *(const uint4*)(A + (size_t)(m0 + row) * lda + kb + kcc);
                vb[i] = *(const uint4*)(Bm + (size_t)(n0 + row) * ldb + kb + kcc);
            }
            for (int i = 0; i < 4; ++i) {
                int q = tid + i * 256;
                int row = q >> 3, kcc = (q & 7) << 3;
                *(uint4*)&As[row * 72 + kcc] = va[i];
                *(uint4*)&Bs[row * 72 + kcc] = vb[i];
            }
        }
        __syncthreads();
        for (int ks = 0; ks < 2; ++ks) {
            short8 a[4], b[4];
            int kk = ks * 32 + (lane >> 4) * 8;
            for (int mi = 0; mi < 4; ++mi)
                a[mi] = *(const short8*)&As[(wr * 64 + mi * 16 + (lane & 15)) * 72 + kk];
            for (int ni = 0; ni < 4; ++ni)
                b[ni] = *(const short8*)&Bs[(wc * 64 + ni * 16 + (lane & 15)) * 72 + kk];
            for (int mi = 0; mi < 4; ++mi)
                for (int ni = 0; ni < 4; ++ni)
                    acc[mi][ni] = __builtin_amdgcn_mfma_f32_16x16x32_bf16(a[mi], b[ni], acc[mi][ni], 0, 0, 0);
        }
    }
    int mb0 = m0 + wr * 64 + ((lane >> 4) << 2);
    int nb0 = n0 + wc * 64 + (lane & 15);
    for (int mi = 0; mi < 4; ++mi) {
        for (int ni = 0; ni < 4; ++ni) {
            int mbase = mb0 + mi * 16;
            int n = nb0 + ni * 16;
            if (EPI == 0) {
                ushort_t* M2T = (ushort_t*)C0;
                int h = n >> 7, e = n & 127;
                size_t base = ((size_t)h << 16) + e;
                for (int r = 0; r < 4; ++r)
                    M2T[base + (size_t)(mbase + r) * 128] = f2bf(acc[mi][ni][r]);
            } else if (EPI == 1) {
                float* h2 = (float*)C0;
                for (int r = 0; r < 4; ++r)
                    atomicAdd(h2 + (size_t)(mbase + r) * 256 + n, acc[mi][ni][r]);
            } else if (EPI == 2) {
                float* s = (float*)C0;
                ushort_t* hl = (ushort_t*)C1;
                float* h2c = (float*)C2;
                for (int r = 0; r < 4; ++r) {
                    int m = mbase + r;
                    float v = acc[mi][ni][r];
                    if (n < 512) s[(size_t)m * 512 + n] = v;
                    else if (n < 768) hl[(size_t)m * 256 + (n - 512)] = f2bf(leaky_(v + aux[n - 512]));
                    else h2c[(size_t)m * 256 + (n - 768)] = v;
                }
            } else if (EPI == 4) {
                ushort_t* P2T = (ushort_t*)C0;
                ushort4 o;
                o.x = f2bf(acc[mi][ni][0]);
                o.y = f2bf(acc[mi][ni][1]);
                o.z = f2bf(acc[mi][ni][2]);
                o.w = f2bf(acc[mi][ni][3]);
                *(ushort4*)(P2T + (size_t)n * 256 + mbase) = o;
            } else if (EPI == 5) {
                float* h2b = (float*)C0;
                const float* h2c = (const float*)C1;
                for (int r = 0; r < 4; ++r) {
                    int m = mbase + r;
                    h2b[(size_t)m * 256 + n] = acc[mi][ni][r] + aux[n] + h2c[(size_t)m * 256 + n];
                }
            }
        }
    }
}

// ---------------- K7: assemble Yp[bn][k*128+e] = bf16(softshrink(s*Atab[r]+Btab[r])) ----------------
__global__ __launch_bounds__(256) void k_assemble_Y(const float* __restrict__ s,
                                                    const ushort_t* __restrict__ Atab, const ushort_t* __restrict__ Btab,
                                                    const float* __restrict__ bpkey,
                                                    ushort_t* __restrict__ Yp) {
    __shared__ float bp_s[256];
    int bn = blockIdx.x >> 1;
    int k = ((blockIdx.x & 1) << 8) + threadIdx.x;
    bp_s[threadIdx.x] = bpkey[threadIdx.x];
    __syncthreads();
    float sv = s[(size_t)bn * 512 + k];
    int lo = 0, hi = 256;
    while (lo < hi) { int mid = (lo + hi) >> 1; if (bp_s[mid] <= sv) lo = mid + 1; else hi = mid; }
    int r = lo;
    const ushort_t* arow = Atab + r * 128;
    const ushort_t* brow = Btab + r * 128;
    ushort_t* dst = Yp + (size_t)bn * 65536 + (size_t)k * 128;
    for (int eb = 0; eb < 16; ++eb) {
        short8 a8 = *(const short8*)(arow + eb * 8);
        short8 b8 = *(const short8*)(brow + eb * 8);
        short8 o;
        for (int j = 0; j < 8; ++j) {
            float y = sv * bf2f((ushort_t)a8[j]) + bf2f((ushort_t)b8[j]);
            y = (y > LAMBDA_) ? (y - LAMBDA_) : ((y < -LAMBDA_) ? (y + LAMBDA_) : 0.f);
            o[j] = (short)f2bf(y);
        }
        *(short8*)(dst + eb * 8) = o;
    }
}

// ---------------- K10: final: a = leaky(h2+h2b+fb1); out = a@fw2+fb2 (transposed store) ----------------
__global__ __launch_bounds__(128) void k_final(const float* __restrict__ h2, const float* __restrict__ h2b,
                                               const float* __restrict__ fb1,
                                               const float* __restrict__ fw2, const float* __restrict__ fb2,
                                               float* __restrict__ out) {
    __shared__ float a_s[256];
    int bn = blockIdx.x;
    int tid = threadIdx.x;
    for (int i = tid; i < 256; i += 128)
        a_s[i] = leaky_(h2[(size_t)bn * 256 + i] + h2b[(size_t)bn * 256 + i] + fb1[i]);
    __syncthreads();
    if (tid < 96) {
        float acc = fb2[tid];
        for (int hh = 0; hh < 256; ++hh)
            acc += a_s[hh] * fw2[hh * 96 + tid];
        int b = bn >> 6, n = bn & 63;
        out[(size_t)(b * 96 + tid) * 64 + n] = acc;
    }
}

extern "C" void kernel_launch(void* const* d_in, const int* in_sizes, int n_in,
                              void* d_out, int out_size, void* d_ws, size_t ws_size,
                              hipStream_t stream) {
    const float* x   = (const float*)d_in[0];
    const float* emb = (const float*)d_in[1];
    const float* w1  = (const float*)d_in[2];
    const float* b1  = (const float*)d_in[3];
    const float* w2  = (const float*)d_in[4];
    const float* b2  = (const float*)d_in[5];
    const float* tw1 = (const float*)d_in[6];
    const float* tb1 = (const float*)d_in[7];
    const float* tw2 = (const float*)d_in[8];
    const float* tb2 = (const float*)d_in[9];
    const float* fw1 = (const float*)d_in[10];
    const float* fb1 = (const float*)d_in[11];
    const float* fw2 = (const float*)d_in[12];
    const float* fb2 = (const float*)d_in[13];
    float* out = (float*)d_out;

    char* W = (char*)d_ws;
    size_t off = 0;
    auto take = [&](size_t bytes) { size_t r = off; off += (bytes + 255) & ~(size_t)255; return r; };
    ushort_t* Yp    = (ushort_t*)(W + take(67108864));       // [512][65536] bf16 (k'=k*128+e)
    ushort_t* fw1T  = Yp;                                    // alias: [32768 j''=h*128+e][512 t], dead before Yp
    ushort_t* M2T   = (ushort_t*)(W + take(33554432));       // [256 h][65536 k']
    ushort_t* A1cat = (ushort_t*)(W + take(512 * 1536 * 2));
    ushort_t* B1cat = (ushort_t*)(W + take(1024 * 1536 * 2));
    ushort_t* Wt    = (ushort_t*)(W + take(512 * 512 * 2));
    ushort_t* tw2bf = (ushort_t*)(W + take(256 * 512 * 2));
    float* F1sT     = (float*)(W + take(256 * 512 * 4 * 2)); // F1sT then F1eT, one memset
    float* F1eT     = F1sT + 256 * 512;
    ushort_t* F1sbf = (ushort_t*)(W + take(256 * 512 * 2));
    float* sbuf     = (float*)(W + take(512 * 512 * 4));
    ushort_t* hlbuf = (ushort_t*)(W + take(512 * 256 * 2));
    float* h2c      = (float*)(W + take(512 * 256 * 4));
    ushort_t* P2T   = (ushort_t*)(W + take(256 * 256 * 2));
    float* p2v      = (float*)(W + take(256 * 4));
    ushort_t* Atab  = (ushort_t*)(W + take(257 * 128 * 2));
    ushort_t* Btab  = (ushort_t*)(W + take(257 * 128 * 2));
    float* bpkey    = (float*)(W + take(256 * 4));
    float* h2       = (float*)(W + take(512 * 256 * 4));
    float* h2b      = (float*)(W + take(512 * 256 * 4));
    (void)ws_size; (void)in_sizes; (void)n_in; (void)out_size;

    hipMemsetAsync(F1sT, 0, 256 * 512 * 4 * 2, stream);
    hipMemsetAsync(h2, 0, 512 * 256 * 4, stream);

    k_setup<<<3072, 256, 0, stream>>>(tw2, B1cat, Wt, tw2bf);
    k_pack_tw1<<<32, 256, 0, stream>>>(tw1, B1cat);
    k_transpose_x<<<256, 256, 0, stream>>>(x, A1cat);
    k_prep<<<1, 256, 0, stream>>>(emb, w1, b1, w2, b2, Atab, Btab, bpkey);
    k_transpose_fw1<<<256, 256, 0, stream>>>(fw1, emb, fw1T, F1sT, F1eT);
    k_pack_F<<<256, 64, 0, stream>>>(F1sT, F1eT, tb2, B1cat, F1sbf, p2v);
    // G1: [s | hl | h2c] = xTcat @ B1cat^T   (M=512, N=1024, K=1536 hi/lo)
    k_mfma<2><<<32, 256, 0, stream>>>(A1cat, B1cat, 1536, 1536, 24, 8, sbuf, hlbuf, h2c, tb1);
    // GEMM0: M2T = Wt @ fw1T^T  (M=512 k, N=32768 j'', K=512 t)
    k_mfma<0><<<1024, 256, 0, stream>>>(Wt, fw1T, 512, 512, 8, 256, M2T, nullptr, nullptr, nullptr);
    // P2' = tw2 @ F1s  (M=256 h'', N=256 h', K=512 t) -> P2T
    k_mfma<4><<<4, 256, 0, stream>>>(tw2bf, F1sbf, 512, 512, 8, 2, P2T, nullptr, nullptr, nullptr);
    // Yp = softshrink tables applied to s
    k_assemble_Y<<<1024, 256, 0, stream>>>(sbuf, Atab, Btab, bpkey, Yp);
    // h2 = Yp @ M2T^T  (M=512, N=256, K=65536, split-K 32, atomics)
    k_mfma<1><<<256, 256, 0, stream>>>(Yp, M2T, 65536, 65536, 32, 2, h2, nullptr, nullptr, nullptr);
    // h2b = hl @ P2'^T + p2v + h2c  (M=512, N=256, K=256)
    k_mfma<5><<<8, 256, 0, stream>>>(hlbuf, P2T, 256, 256, 4, 2, h2b, h2c, nullptr, p2v);
    k_final<<<512, 128, 0, stream>>>(h2, h2b, fb1, fw2, fb2, out);
}

// Round 3
// 292.607 us; speedup vs baseline: 1.4541x; 1.4541x over previous
//
#include <hip/hip_runtime.h>
#include <hip/hip_bf16.h>

// B=8, T=512, N=64, E=128, H=256, P=96.  bn = b*64+n (512 rows).
// Identities:
//  xe = x_noD*emb  => rfft factorizes: spectral scalar s[bn,k] (packed: k<=256 real, k>256 imag)
//  mlp(s*emb) piecewise-linear in s (257 regions; tables Atab/Btab[r][e])
//  xt-part of flat@fw1:  h2[bn,h] = sum_{k,e} Yp[bn,k,e] * M2[k,e,h],
//      M2[k,(h,e)] = sum_t W[t,k] fw1[(t*128+e)*256+h]   (W = packed irfft basis)
//  xn-part:   xn@F1s = hl@(tw2@F1s) + tb2@F1s,  F1s[t,h] = sum_e fw1
//  bias-part: x_noD@F1e,                        F1e[t,h] = sum_e (1+emb_e) fw1
//  s and x@F1e computed via hi/lo bf16 K-concat MFMA (A=[hi|lo|hi], B=[hi;hi;lo]).

typedef unsigned int uint;
typedef unsigned short ushort_t;
typedef __attribute__((ext_vector_type(4))) float f32x4;
typedef __attribute__((ext_vector_type(8))) short short8;

#define LAMBDA_ 0.001f
#define RSQRT512 0.044194173824159220f

__device__ __forceinline__ ushort_t f2bf(float f) {
    uint u = __float_as_uint(f);
    uint r = (u + 0x7FFFu + ((u >> 16) & 1u)) >> 16;
    return (ushort_t)r;
}
__device__ __forceinline__ float bf2f(ushort_t v) { return __uint_as_float(((uint)v) << 16); }
__device__ __forceinline__ float leaky_(float v) { return v >= 0.f ? v : 0.01f * v; }

// ---------------- K0: transpose x [8][512][64] -> A1cat [512 bn][1536] (hi|lo|hi) ----------------
__global__ __launch_bounds__(256) void k_transpose_x(const float* __restrict__ x, ushort_t* __restrict__ A1cat) {
    __shared__ float tile[32][33];
    int bid = blockIdx.x;             // 8 * 16 * 2 = 256
    int b = bid >> 5;
    int rem = bid & 31;
    int t0 = (rem >> 1) << 5;
    int n0 = (rem & 1) << 5;
    int tx = threadIdx.x & 31, ty = threadIdx.x >> 5;
    for (int i = 0; i < 4; ++i) {
        int tt = ty * 4 + i;
        tile[tt][tx] = x[(size_t)(b * 512 + t0 + tt) * 64 + n0 + tx];
    }
    __syncthreads();
    for (int i = 0; i < 4; ++i) {
        int nn = ty * 4 + i;
        float v = tile[tx][nn];
        ushort_t hi = f2bf(v);
        ushort_t lo = f2bf(v - bf2f(hi));
        size_t row = (size_t)(b * 64 + n0 + nn) * 1536;
        int t = t0 + tx;
        A1cat[row + t] = hi;
        A1cat[row + 512 + t] = lo;
        A1cat[row + 1024 + t] = hi;
    }
}

// ---------------- K1: setup — B1cat DFT rows, Wt, tw2_bf ----------------
__global__ __launch_bounds__(256) void k_setup(const float* __restrict__ tw2,
                                               ushort_t* __restrict__ B1cat, ushort_t* __restrict__ Wt,
                                               ushort_t* __restrict__ tw2_bf) {
    int bid = blockIdx.x;
    int region = bid >> 10;
    int id = ((bid & 1023) << 8) + threadIdx.x;
    int a = id >> 9, c = id & 511;
    if (region == 0) {       // B1cat rows 0-511: D[t=c][k=a]
        int f = (a <= 256) ? a : (a - 256);
        int m = (c * f) & 511;
        float ang = (float)m * (6.283185307179586f / 512.0f);
        float v = ((a <= 256) ? cosf(ang) : -sinf(ang)) * RSQRT512;
        ushort_t hi = f2bf(v);
        ushort_t lo = f2bf(v - bf2f(hi));
        size_t row = (size_t)a * 1536;
        B1cat[row + c] = hi;
        B1cat[row + 512 + c] = hi;
        B1cat[row + 1024 + c] = lo;
    } else if (region == 1) {  // Wt[k=a][t=c]
        int f = (a <= 256) ? a : (a - 256);
        int m = (c * f) & 511;
        float ang = (float)m * (6.283185307179586f / 512.0f);
        float v = ((a <= 256) ? cosf(ang) : -sinf(ang)) * RSQRT512;
        float sc = (a == 0 || a == 256) ? 1.0f : 2.0f;
        Wt[id] = f2bf(v * sc);
    } else {                   // tw2_bf: 512 blocks used
        if ((bid & 1023) < 512) tw2_bf[id] = f2bf(tw2[id]);
    }
}

// ---------------- K2: pack tw1 -> B1cat rows 512-767 (transposed, hi|hi|lo) ----------------
__global__ __launch_bounds__(256) void k_pack_tw1(const float* __restrict__ tw1, ushort_t* __restrict__ B1cat) {
    __shared__ float tile[64][65];
    int bid = blockIdx.x;            // 8 t-tiles * 4 h-tiles = 32
    int t0 = (bid & 7) << 6, h0 = (bid >> 3) << 6;
    int tid = threadIdx.x;
    for (int i = 0; i < 16; ++i) {
        int idx = tid + i * 256;
        int r = idx >> 6, cc = idx & 63;
        tile[r][cc] = tw1[(size_t)(t0 + r) * 256 + h0 + cc];
    }
    __syncthreads();
    for (int i = 0; i < 16; ++i) {
        int idx = tid + i * 256;
        int rr = idx >> 6, cc2 = idx & 63;      // rr: h, cc2: t
        float v = tile[cc2][rr];
        ushort_t hi = f2bf(v);
        ushort_t lo = f2bf(v - bf2f(hi));
        size_t row = (size_t)(512 + h0 + rr) * 1536;
        int t = t0 + cc2;
        B1cat[row + t] = hi;
        B1cat[row + 512 + t] = hi;
        B1cat[row + 1024 + t] = lo;
    }
}

// ---------------- K3: piecewise-linear tables (1 block) ----------------
__global__ __launch_bounds__(256) void k_prep(const float* __restrict__ emb, const float* __restrict__ w1,
                                              const float* __restrict__ b1, const float* __restrict__ w2,
                                              const float* __restrict__ b2,
                                              ushort_t* __restrict__ Atab, ushort_t* __restrict__ Btab,
                                              float* __restrict__ bpkey_g) {
    __shared__ float u_s[256], b1_s[256], key_s[256];
    __shared__ int idx_s[256];
    int tid = threadIdx.x;
    float acc = 0.f;
    for (int e = 0; e < 128; ++e) acc += emb[e] * w1[e * 256 + tid];
    u_s[tid] = acc;
    float bb0 = b1[tid];
    b1_s[tid] = bb0;
    key_s[tid] = (acc == 0.f) ? INFINITY : (-bb0 / acc);
    idx_s[tid] = tid;
    __syncthreads();
    for (int k = 2; k <= 256; k <<= 1) {
        for (int j = k >> 1; j > 0; j >>= 1) {
            int ixj = tid ^ j;
            if (ixj > tid) {
                bool up = ((tid & k) == 0);
                float a0 = key_s[tid], a1 = key_s[ixj];
                if ((a0 > a1) == up) {
                    key_s[tid] = a1; key_s[ixj] = a0;
                    int t0 = idx_s[tid]; idx_s[tid] = idx_s[ixj]; idx_s[ixj] = t0;
                }
            }
            __syncthreads();
        }
    }
    bpkey_g[tid] = key_s[tid];
    if (tid < 128) {
        int e = tid;
        float aA = 0.f, aB = 0.f;
        for (int h = 0; h < 256; ++h) {
            float uu = u_s[h], bbh = b1_s[h];
            float c = (uu < 0.f || (uu == 0.f && bbh >= 0.f)) ? 1.0f : 0.01f;
            float w = w2[h * 128 + e];
            aA += c * uu * w;
            aB += c * bbh * w;
        }
        aB += b2[e];
        Atab[e] = f2bf(aA);
        Btab[e] = f2bf(aB);
        for (int r = 1; r <= 256; ++r) {
            int h = idx_s[r - 1];
            float uu = u_s[h], bbh = b1_s[h];
            float w = w2[h * 128 + e];
            float sgn = (uu > 0.f) ? 0.99f : -0.99f;
            aA += sgn * uu * w;
            aB += sgn * bbh * w;
            Atab[r * 128 + e] = f2bf(aA);
            Btab[r * 128 + e] = f2bf(aB);
        }
    }
}

// ---------------- K4: transpose fw1 [(t,e)][h] f32 -> fw1T[(h*128+e)][t] bf16 ----------------
// grid 4096 = e(128, innermost) x hb(4) x tt(8); per block: 64t x 64h tile for one e.
__global__ __launch_bounds__(256) void k_transpose_fw1(const float* __restrict__ fw1, ushort_t* __restrict__ fw1T) {
    __shared__ float tile[64][65];
    int bid = blockIdx.x;
    int e  = bid & 127;
    int hb = (bid >> 7) & 3;
    int tt = bid >> 9;
    int t0 = tt << 6, h0 = hb << 6;
    int tid = threadIdx.x;
    for (int i = 0; i < 4; ++i) {
        int idx = tid + i * 256;            // 0..1023 float4s
        int r = idx >> 4, c4 = idx & 15;
        const float* src = fw1 + ((size_t)(t0 + r) * 128 + e) * 256 + h0 + c4 * 4;
        float4 v = *(const float4*)src;
        tile[r][c4 * 4 + 0] = v.x;
        tile[r][c4 * 4 + 1] = v.y;
        tile[r][c4 * 4 + 2] = v.z;
        tile[r][c4 * 4 + 3] = v.w;
    }
    __syncthreads();
    for (int p = 0; p < 2; ++p) {
        int idx = tid + p * 256;            // 0..511 short8s
        int hh = idx >> 3, tg = idx & 7;
        short8 o;
        for (int j = 0; j < 8; ++j) o[j] = (short)f2bf(tile[tg * 8 + j][hh]);
        *(short8*)(fw1T + ((size_t)(h0 + hh) * 128 + e) * 512 + t0 + tg * 8) = o;
    }
}

// ---------------- K4b: F1s/F1e reduce over e: F1th[0][t][h]=sum_e fw1, F1th[1][t][h]=sum_e(1+emb)fw1 ----------------
__global__ __launch_bounds__(256) void k_reduce_F(const float* __restrict__ fw1, const float* __restrict__ emb,
                                                  float* __restrict__ F1th) {
    __shared__ float embs[128];
    int t = blockIdx.x;
    int h = threadIdx.x;
    if (h < 128) embs[h] = 1.f + emb[h];
    __syncthreads();
    const float* base = fw1 + (size_t)t * 32768 + h;
    float as = 0.f, ae = 0.f;
#pragma unroll 4
    for (int e = 0; e < 128; ++e) {
        float v = base[(size_t)e * 256];
        as += v;
        ae += embs[e] * v;
    }
    F1th[(size_t)t * 256 + h] = as;
    F1th[131072 + (size_t)t * 256 + h] = ae;
}

// ---------------- K4c: transpose F1th [2][512 t][256 h] -> F1T [2][256 h][512 t] ----------------
__global__ __launch_bounds__(256) void k_transpose_F(const float* __restrict__ src, float* __restrict__ dst) {
    __shared__ float tile[64][65];
    int bid = blockIdx.x;                 // 64 = arr(2) x hb(4) x tt(8)
    int arr = bid & 1, hb = (bid >> 1) & 3, tt = bid >> 3;
    int t0 = tt << 6, h0 = hb << 6;
    size_t ab = (size_t)arr * 131072;
    int tid = threadIdx.x;
    for (int i = 0; i < 16; ++i) {
        int idx = tid + i * 256;
        int r = idx >> 6, c = idx & 63;   // r: t, c: h
        tile[r][c] = src[ab + (size_t)(t0 + r) * 256 + h0 + c];
    }
    __syncthreads();
    for (int i = 0; i < 16; ++i) {
        int idx = tid + i * 256;
        int r = idx >> 6, c = idx & 63;   // r: h, c: t
        dst[ab + (size_t)(h0 + r) * 512 + t0 + c] = tile[c][r];
    }
}

// ---------------- K5: pack F1s/F1e: B1cat rows 768-1023 (F1e hi|hi|lo), F1sT_bf, p2v = tb2@F1s ----------------
__global__ __launch_bounds__(64) void k_pack_F(const float* __restrict__ F1sT, const float* __restrict__ F1eT,
                                               const float* __restrict__ tb2,
                                               ushort_t* __restrict__ B1cat, ushort_t* __restrict__ F1sT_bf,
                                               float* __restrict__ p2v) {
    int h = blockIdx.x;                   // 256
    int lane = threadIdx.x;
    int t = lane * 8;
    float p2 = 0.f;
    short8 shi, ehi, elo;
    for (int j = 0; j < 8; ++j) {
        float vs = F1sT[(size_t)h * 512 + t + j];
        float ve = F1eT[(size_t)h * 512 + t + j];
        p2 += tb2[t + j] * vs;
        shi[j] = (short)f2bf(vs);
        ushort_t hi = f2bf(ve);
        ehi[j] = (short)hi;
        elo[j] = (short)f2bf(ve - bf2f(hi));
    }
    *(short8*)(F1sT_bf + (size_t)h * 512 + t) = shi;
    size_t row = (size_t)(768 + h) * 1536;
    *(short8*)(B1cat + row + t) = ehi;
    *(short8*)(B1cat + row + 512 + t) = ehi;
    *(short8*)(B1cat + row + 1024 + t) = elo;
    for (int o = 32; o > 0; o >>= 1) p2 += __shfl_xor(p2, o);
    if (lane == 0) p2v[h] = p2;
}

// ---------------- generic 128x128-tile bf16 MFMA GEMM; A [M][K] lda, B [N][K] ldb ----------------
template<int EPI>
__global__ __launch_bounds__(256) void k_mfma(const ushort_t* __restrict__ A, const ushort_t* __restrict__ Bm,
                                              int lda, int ldb, int kIters, int nTiles,
                                              void* __restrict__ C0, void* __restrict__ C1,
                                              void* __restrict__ C2, const float* __restrict__ aux) {
    __shared__ ushort_t As[128 * 72];
    __shared__ ushort_t Bs[128 * 72];
    int tid = threadIdx.x;
    int lane = tid & 63, wid = tid >> 6;
    int wr = wid >> 1, wc = wid & 1;
    int bid = blockIdx.x;
    int mt, nt, kc = 0;
    if (EPI == 1) {
        int xx = bid & 7, y = bid >> 3;
        kc = ((y & 3) << 3) | xx;
        int mem = y >> 2;
        mt = mem >> 1; nt = mem & 1;
    } else if (EPI == 0) {
        int xx = bid & 7, y = bid >> 3;
        mt = y & 3;
        nt = ((y >> 2) << 3) | xx;
    } else {
        nt = bid % nTiles;
        mt = bid / nTiles;
    }
    int m0 = mt * 128, n0 = nt * 128, k0 = kc * (kIters * 64);
    f32x4 acc[4][4] = {};
    for (int kt = 0; kt < kIters; ++kt) {
        int kb = k0 + kt * 64;
        __syncthreads();
        {
            uint4 va[4], vb[4];
            for (int i = 0; i < 4; ++i) {
                int q = tid + i * 256;
                int row = q >> 3, kcc = (q & 7) << 3;
                va[i] = *(const uint4*)(A + (size_t)(m0 + row) * lda + kb + kcc);
                vb[i] = *(const uint4*)(Bm + (size_t)(n0 + row) * ldb + kb + kcc);
            }
            for (int i = 0; i < 4; ++i) {
                int q = tid + i * 256;
                int row = q >> 3, kcc = (q & 7) << 3;
                *(uint4*)&As[row * 72 + kcc] = va[i];
                *(uint4*)&Bs[row * 72 + kcc] = vb[i];
            }
        }
        __syncthreads();
        for (int ks = 0; ks < 2; ++ks) {
            short8 a[4], b[4];
            int kk = ks * 32 + (lane >> 4) * 8;
            for (int mi = 0; mi < 4; ++mi)
                a[mi] = *(const short8*)&As[(wr * 64 + mi * 16 + (lane & 15)) * 72 + kk];
            for (int ni = 0; ni < 4; ++ni)
                b[ni] = *(const short8*)&Bs[(wc * 64 + ni * 16 + (lane & 15)) * 72 + kk];
            for (int mi = 0; mi < 4; ++mi)
                for (int ni = 0; ni < 4; ++ni)
                    acc[mi][ni] = __builtin_amdgcn_mfma_f32_16x16x32_bf16(a[mi], b[ni], acc[mi][ni], 0, 0, 0);
        }
    }
    int mb0 = m0 + wr * 64 + ((lane >> 4) << 2);
    int nb0 = n0 + wc * 64 + (lane & 15);
    for (int mi = 0; mi < 4; ++mi) {
        for (int ni = 0; ni < 4; ++ni) {
            int mbase = mb0 + mi * 16;
            int n = nb0 + ni * 16;
            if (EPI == 0) {
                ushort_t* M2T = (ushort_t*)C0;
                int h = n >> 7, e = n & 127;
                size_t base = ((size_t)h << 16) + e;
                for (int r = 0; r < 4; ++r)
                    M2T[base + (size_t)(mbase + r) * 128] = f2bf(acc[mi][ni][r]);
            } else if (EPI == 1) {
                float* h2 = (float*)C0;
                for (int r = 0; r < 4; ++r)
                    atomicAdd(h2 + (size_t)(mbase + r) * 256 + n, acc[mi][ni][r]);
            } else if (EPI == 2) {
                float* s = (float*)C0;
                ushort_t* hl = (ushort_t*)C1;
                float* h2c = (float*)C2;
                for (int r = 0; r < 4; ++r) {
                    int m = mbase + r;
                    float v = acc[mi][ni][r];
                    if (n < 512) s[(size_t)m * 512 + n] = v;
                    else if (n < 768) hl[(size_t)m * 256 + (n - 512)] = f2bf(leaky_(v + aux[n - 512]));
                    else h2c[(size_t)m * 256 + (n - 768)] = v;
                }
            } else if (EPI == 4) {
                ushort_t* P2T = (ushort_t*)C0;
                ushort4 o;
                o.x = f2bf(acc[mi][ni][0]);
                o.y = f2bf(acc[mi][ni][1]);
                o.z = f2bf(acc[mi][ni][2]);
                o.w = f2bf(acc[mi][ni][3]);
                *(ushort4*)(P2T + (size_t)n * 256 + mbase) = o;
            } else if (EPI == 5) {
                float* h2b = (float*)C0;
                const float* h2c = (const float*)C1;
                for (int r = 0; r < 4; ++r) {
                    int m = mbase + r;
                    h2b[(size_t)m * 256 + n] = acc[mi][ni][r] + aux[n] + h2c[(size_t)m * 256 + n];
                }
            }
        }
    }
}

// ---------------- K7: assemble Yp[bn][k*128+e] = bf16(softshrink(s*Atab[r]+Btab[r])) ----------------
__global__ __launch_bounds__(256) void k_assemble_Y(const float* __restrict__ s,
                                                    const ushort_t* __restrict__ Atab, const ushort_t* __restrict__ Btab,
                                                    const float* __restrict__ bpkey,
                                                    ushort_t* __restrict__ Yp) {
    __shared__ float bp_s[256];
    int bn = blockIdx.x >> 1;
    int k = ((blockIdx.x & 1) << 8) + threadIdx.x;
    bp_s[threadIdx.x] = bpkey[threadIdx.x];
    __syncthreads();
    float sv = s[(size_t)bn * 512 + k];
    int lo = 0, hi = 256;
    while (lo < hi) { int mid = (lo + hi) >> 1; if (bp_s[mid] <= sv) lo = mid + 1; else hi = mid; }
    int r = lo;
    const ushort_t* arow = Atab + r * 128;
    const ushort_t* brow = Btab + r * 128;
    ushort_t* dst = Yp + (size_t)bn * 65536 + (size_t)k * 128;
    for (int eb = 0; eb < 16; ++eb) {
        short8 a8 = *(const short8*)(arow + eb * 8);
        short8 b8 = *(const short8*)(brow + eb * 8);
        short8 o;
        for (int j = 0; j < 8; ++j) {
            float y = sv * bf2f((ushort_t)a8[j]) + bf2f((ushort_t)b8[j]);
            y = (y > LAMBDA_) ? (y - LAMBDA_) : ((y < -LAMBDA_) ? (y + LAMBDA_) : 0.f);
            o[j] = (short)f2bf(y);
        }
        *(short8*)(dst + eb * 8) = o;
    }
}

// ---------------- K10: final ----------------
__global__ __launch_bounds__(128) void k_final(const float* __restrict__ h2, const float* __restrict__ h2b,
                                               const float* __restrict__ fb1,
                                               const float* __restrict__ fw2, const float* __restrict__ fb2,
                                               float* __restrict__ out) {
    __shared__ float a_s[256];
    int bn = blockIdx.x;
    int tid = threadIdx.x;
    for (int i = tid; i < 256; i += 128)
        a_s[i] = leaky_(h2[(size_t)bn * 256 + i] + h2b[(size_t)bn * 256 + i] + fb1[i]);
    __syncthreads();
    if (tid < 96) {
        float acc = fb2[tid];
        for (int hh = 0; hh < 256; ++hh)
            acc += a_s[hh] * fw2[hh * 96 + tid];
        int b = bn >> 6, n = bn & 63;
        out[(size_t)(b * 96 + tid) * 64 + n] = acc;
    }
}

extern "C" void kernel_launch(void* const* d_in, const int* in_sizes, int n_in,
                              void* d_out, int out_size, void* d_ws, size_t ws_size,
                              hipStream_t stream) {
    const float* x   = (const float*)d_in[0];
    const float* emb = (const float*)d_in[1];
    const float* w1  = (const float*)d_in[2];
    const float* b1  = (const float*)d_in[3];
    const float* w2  = (const float*)d_in[4];
    const float* b2  = (const float*)d_in[5];
    const float* tw1 = (const float*)d_in[6];
    const float* tb1 = (const float*)d_in[7];
    const float* tw2 = (const float*)d_in[8];
    const float* tb2 = (const float*)d_in[9];
    const float* fw1 = (const float*)d_in[10];
    const float* fb1 = (const float*)d_in[11];
    const float* fw2 = (const float*)d_in[12];
    const float* fb2 = (const float*)d_in[13];
    float* out = (float*)d_out;

    char* W = (char*)d_ws;
    size_t off = 0;
    auto take = [&](size_t bytes) { size_t r = off; off += (bytes + 255) & ~(size_t)255; return r; };
    ushort_t* Yp    = (ushort_t*)(W + take(67108864));       // [512][65536] bf16 (k'=k*128+e)
    ushort_t* fw1T  = Yp;                                    // alias: [32768 j''=h*128+e][512 t], dead before Yp
    ushort_t* M2T   = (ushort_t*)(W + take(33554432));       // [256 h][65536 k']
    ushort_t* A1cat = (ushort_t*)(W + take(512 * 1536 * 2));
    ushort_t* B1cat = (ushort_t*)(W + take(1024 * 1536 * 2));
    ushort_t* Wt    = (ushort_t*)(W + take(512 * 512 * 2));
    ushort_t* tw2bf = (ushort_t*)(W + take(256 * 512 * 2));
    float* F1th     = (float*)(W + take(2 * 512 * 256 * 4)); // [2][t][h]
    float* F1T      = (float*)(W + take(2 * 256 * 512 * 4)); // [2][h][t]
    ushort_t* F1sbf = (ushort_t*)(W + take(256 * 512 * 2));
    float* sbuf     = (float*)(W + take(512 * 512 * 4));
    ushort_t* hlbuf = (ushort_t*)(W + take(512 * 256 * 2));
    float* h2c      = (float*)(W + take(512 * 256 * 4));
    ushort_t* P2T   = (ushort_t*)(W + take(256 * 256 * 2));
    float* p2v      = (float*)(W + take(256 * 4));
    ushort_t* Atab  = (ushort_t*)(W + take(257 * 128 * 2));
    ushort_t* Btab  = (ushort_t*)(W + take(257 * 128 * 2));
    float* bpkey    = (float*)(W + take(256 * 4));
    float* h2       = (float*)(W + take(512 * 256 * 4));
    float* h2b      = (float*)(W + take(512 * 256 * 4));
    (void)ws_size; (void)in_sizes; (void)n_in; (void)out_size;

    hipMemsetAsync(h2, 0, 512 * 256 * 4, stream);

    k_setup<<<3072, 256, 0, stream>>>(tw2, B1cat, Wt, tw2bf);
    k_pack_tw1<<<32, 256, 0, stream>>>(tw1, B1cat);
    k_transpose_x<<<256, 256, 0, stream>>>(x, A1cat);
    k_prep<<<1, 256, 0, stream>>>(emb, w1, b1, w2, b2, Atab, Btab, bpkey);
    k_transpose_fw1<<<4096, 256, 0, stream>>>(fw1, fw1T);
    k_reduce_F<<<512, 256, 0, stream>>>(fw1, emb, F1th);
    k_transpose_F<<<64, 256, 0, stream>>>(F1th, F1T);
    k_pack_F<<<256, 64, 0, stream>>>(F1T, F1T + 131072, tb2, B1cat, F1sbf, p2v);
    // G1: [s | hl | h2c] = xTcat @ B1cat^T   (M=512, N=1024, K=1536 hi/lo)
    k_mfma<2><<<32, 256, 0, stream>>>(A1cat, B1cat, 1536, 1536, 24, 8, sbuf, hlbuf, h2c, tb1);
    // GEMM0: M2T = Wt @ fw1T^T  (M=512 k, N=32768 j'', K=512 t)
    k_mfma<0><<<1024, 256, 0, stream>>>(Wt, fw1T, 512, 512, 8, 256, M2T, nullptr, nullptr, nullptr);
    // P2' = tw2 @ F1s  (M=256 h'', N=256 h', K=512 t) -> P2T
    k_mfma<4><<<4, 256, 0, stream>>>(tw2bf, F1sbf, 512, 512, 8, 2, P2T, nullptr, nullptr, nullptr);
    // Yp = softshrink tables applied to s
    k_assemble_Y<<<1024, 256, 0, stream>>>(sbuf, Atab, Btab, bpkey, Yp);
    // h2 = Yp @ M2T^T  (M=512, N=256, K=65536, split-K 32, atomics)
    k_mfma<1><<<256, 256, 0, stream>>>(Yp, M2T, 65536, 65536, 32, 2, h2, nullptr, nullptr, nullptr);
    // h2b = hl @ P2'^T + p2v + h2c  (M=512, N=256, K=256)
    k_mfma<5><<<8, 256, 0, stream>>>(hlbuf, P2T, 256, 256, 4, 2, h2b, h2c, nullptr, p2v);
    k_final<<<512, 128, 0, stream>>>(h2, h2b, fb1, fw2, fb2, out);
}

// Round 4
// 267.208 us; speedup vs baseline: 1.5923x; 1.0951x over previous
//
#include <hip/hip_runtime.h>
#include <hip/hip_bf16.h>

// B=8, T=512, N=64, E=128, H=256, P=96.  bn = b*64+n (512 rows).
// Identities:
//  xe = x_noD*emb  => rfft factorizes: spectral scalar s[bn,k] (packed: k<=256 real, k>256 imag)
//  mlp(s*emb) piecewise-linear in s (257 regions; tables Atab/Btab[r][e])
//  xt-part of flat@fw1:  h2[bn,h] = sum_{k,e} Yp[bn,k,e] * M2[k,e,h],
//      M2[k,(h,e)] = sum_t W[t,k] fw1[(t*128+e)*256+h]   (W = packed irfft basis)
//  xn-part:   xn@F1s = hl@(tw2@F1s) + tb2@F1s,  F1s[t,h] = sum_e fw1
//  bias-part: x_noD@F1e,                        F1e[t,h] = sum_e (1+emb_e) fw1
//  s and x@F1e computed via hi/lo bf16 K-concat MFMA (A=[hi|lo|hi], B=[hi;hi;lo]).

typedef unsigned int uint;
typedef unsigned short ushort_t;
typedef __attribute__((ext_vector_type(4))) float f32x4;
typedef __attribute__((ext_vector_type(8))) short short8;

#define LAMBDA_ 0.001f
#define RSQRT512 0.044194173824159220f

__device__ __forceinline__ ushort_t f2bf(float f) {
    uint u = __float_as_uint(f);
    uint r = (u + 0x7FFFu + ((u >> 16) & 1u)) >> 16;
    return (ushort_t)r;
}
__device__ __forceinline__ float bf2f(ushort_t v) { return __uint_as_float(((uint)v) << 16); }
__device__ __forceinline__ float leaky_(float v) { return v >= 0.f ? v : 0.01f * v; }

// ---------------- K0: transpose x [8][512][64] -> A1cat [512 bn][1536] (hi|lo|hi) ----------------
__global__ __launch_bounds__(256) void k_transpose_x(const float* __restrict__ x, ushort_t* __restrict__ A1cat) {
    __shared__ float tile[32][33];
    int bid = blockIdx.x;             // 8 * 16 * 2 = 256
    int b = bid >> 5;
    int rem = bid & 31;
    int t0 = (rem >> 1) << 5;
    int n0 = (rem & 1) << 5;
    int tx = threadIdx.x & 31, ty = threadIdx.x >> 5;
    for (int i = 0; i < 4; ++i) {
        int tt = ty * 4 + i;
        tile[tt][tx] = x[(size_t)(b * 512 + t0 + tt) * 64 + n0 + tx];
    }
    __syncthreads();
    for (int i = 0; i < 4; ++i) {
        int nn = ty * 4 + i;
        float v = tile[tx][nn];
        ushort_t hi = f2bf(v);
        ushort_t lo = f2bf(v - bf2f(hi));
        size_t row = (size_t)(b * 64 + n0 + nn) * 1536;
        int t = t0 + tx;
        A1cat[row + t] = hi;
        A1cat[row + 512 + t] = lo;
        A1cat[row + 1024 + t] = hi;
    }
}

// ---------------- K1: setup — B1cat DFT rows, Wt, tw2_bf ----------------
__global__ __launch_bounds__(256) void k_setup(const float* __restrict__ tw2,
                                               ushort_t* __restrict__ B1cat, ushort_t* __restrict__ Wt,
                                               ushort_t* __restrict__ tw2_bf) {
    int bid = blockIdx.x;
    int region = bid >> 10;
    int id = ((bid & 1023) << 8) + threadIdx.x;
    int a = id >> 9, c = id & 511;
    if (region == 0) {       // B1cat rows 0-511: D[t=c][k=a]
        int f = (a <= 256) ? a : (a - 256);
        int m = (c * f) & 511;
        float ang = (float)m * (6.283185307179586f / 512.0f);
        float v = ((a <= 256) ? cosf(ang) : -sinf(ang)) * RSQRT512;
        ushort_t hi = f2bf(v);
        ushort_t lo = f2bf(v - bf2f(hi));
        size_t row = (size_t)a * 1536;
        B1cat[row + c] = hi;
        B1cat[row + 512 + c] = hi;
        B1cat[row + 1024 + c] = lo;
    } else if (region == 1) {  // Wt[k=a][t=c]
        int f = (a <= 256) ? a : (a - 256);
        int m = (c * f) & 511;
        float ang = (float)m * (6.283185307179586f / 512.0f);
        float v = ((a <= 256) ? cosf(ang) : -sinf(ang)) * RSQRT512;
        float sc = (a == 0 || a == 256) ? 1.0f : 2.0f;
        Wt[id] = f2bf(v * sc);
    } else {                   // tw2_bf: 512 blocks used
        if ((bid & 1023) < 512) tw2_bf[id] = f2bf(tw2[id]);
    }
}

// ---------------- K2: pack tw1 -> B1cat rows 512-767 (transposed, hi|hi|lo) ----------------
__global__ __launch_bounds__(256) void k_pack_tw1(const float* __restrict__ tw1, ushort_t* __restrict__ B1cat) {
    __shared__ float tile[64][65];
    int bid = blockIdx.x;            // 8 t-tiles * 4 h-tiles = 32
    int t0 = (bid & 7) << 6, h0 = (bid >> 3) << 6;
    int tid = threadIdx.x;
    for (int i = 0; i < 16; ++i) {
        int idx = tid + i * 256;
        int r = idx >> 6, cc = idx & 63;
        tile[r][cc] = tw1[(size_t)(t0 + r) * 256 + h0 + cc];
    }
    __syncthreads();
    for (int i = 0; i < 16; ++i) {
        int idx = tid + i * 256;
        int rr = idx >> 6, cc2 = idx & 63;      // rr: h, cc2: t
        float v = tile[cc2][rr];
        ushort_t hi = f2bf(v);
        ushort_t lo = f2bf(v - bf2f(hi));
        size_t row = (size_t)(512 + h0 + rr) * 1536;
        int t = t0 + cc2;
        B1cat[row + t] = hi;
        B1cat[row + 512 + t] = hi;
        B1cat[row + 1024 + t] = lo;
    }
}

// ---------------- K3: piecewise-linear tables (1 block) ----------------
__global__ __launch_bounds__(256) void k_prep(const float* __restrict__ emb, const float* __restrict__ w1,
                                              const float* __restrict__ b1, const float* __restrict__ w2,
                                              const float* __restrict__ b2,
                                              ushort_t* __restrict__ Atab, ushort_t* __restrict__ Btab,
                                              float* __restrict__ bpkey_g) {
    __shared__ float u_s[256], b1_s[256], key_s[256];
    __shared__ int idx_s[256];
    int tid = threadIdx.x;
    float acc = 0.f;
    for (int e = 0; e < 128; ++e) acc += emb[e] * w1[e * 256 + tid];
    u_s[tid] = acc;
    float bb0 = b1[tid];
    b1_s[tid] = bb0;
    key_s[tid] = (acc == 0.f) ? INFINITY : (-bb0 / acc);
    idx_s[tid] = tid;
    __syncthreads();
    for (int k = 2; k <= 256; k <<= 1) {
        for (int j = k >> 1; j > 0; j >>= 1) {
            int ixj = tid ^ j;
            if (ixj > tid) {
                bool up = ((tid & k) == 0);
                float a0 = key_s[tid], a1 = key_s[ixj];
                if ((a0 > a1) == up) {
                    key_s[tid] = a1; key_s[ixj] = a0;
                    int t0 = idx_s[tid]; idx_s[tid] = idx_s[ixj]; idx_s[ixj] = t0;
                }
            }
            __syncthreads();
        }
    }
    bpkey_g[tid] = key_s[tid];
    if (tid < 128) {
        int e = tid;
        float aA = 0.f, aB = 0.f;
        for (int h = 0; h < 256; ++h) {
            float uu = u_s[h], bbh = b1_s[h];
            float c = (uu < 0.f || (uu == 0.f && bbh >= 0.f)) ? 1.0f : 0.01f;
            float w = w2[h * 128 + e];
            aA += c * uu * w;
            aB += c * bbh * w;
        }
        aB += b2[e];
        Atab[e] = f2bf(aA);
        Btab[e] = f2bf(aB);
        for (int r = 1; r <= 256; ++r) {
            int h = idx_s[r - 1];
            float uu = u_s[h], bbh = b1_s[h];
            float w = w2[h * 128 + e];
            float sgn = (uu > 0.f) ? 0.99f : -0.99f;
            aA += sgn * uu * w;
            aB += sgn * bbh * w;
            Atab[r * 128 + e] = f2bf(aA);
            Btab[r * 128 + e] = f2bf(aB);
        }
    }
}

// ---------------- K4: transpose fw1 [(t,e)][h] f32 -> fw1T[(h*128+e)][t] bf16 ----------------
__global__ __launch_bounds__(256) void k_transpose_fw1(const float* __restrict__ fw1, ushort_t* __restrict__ fw1T) {
    __shared__ float tile[64][65];
    int bid = blockIdx.x;
    int e  = bid & 127;
    int hb = (bid >> 7) & 3;
    int tt = bid >> 9;
    int t0 = tt << 6, h0 = hb << 6;
    int tid = threadIdx.x;
    for (int i = 0; i < 4; ++i) {
        int idx = tid + i * 256;            // 0..1023 float4s
        int r = idx >> 4, c4 = idx & 15;
        const float* src = fw1 + ((size_t)(t0 + r) * 128 + e) * 256 + h0 + c4 * 4;
        float4 v = *(const float4*)src;
        tile[r][c4 * 4 + 0] = v.x;
        tile[r][c4 * 4 + 1] = v.y;
        tile[r][c4 * 4 + 2] = v.z;
        tile[r][c4 * 4 + 3] = v.w;
    }
    __syncthreads();
    for (int p = 0; p < 2; ++p) {
        int idx = tid + p * 256;            // 0..511 short8s
        int hh = idx >> 3, tg = idx & 7;
        short8 o;
        for (int j = 0; j < 8; ++j) o[j] = (short)f2bf(tile[tg * 8 + j][hh]);
        *(short8*)(fw1T + ((size_t)(h0 + hh) * 128 + e) * 512 + t0 + tg * 8) = o;
    }
}

// ---------------- K4b: F1 from fw1T: F1T[0][h][t]=sum_e fw1T, F1T[1][h][t]=sum_e(1+emb)fw1T ----------------
__global__ __launch_bounds__(256) void k_reduce_F2(const ushort_t* __restrict__ fw1T, const float* __restrict__ emb,
                                                   float* __restrict__ F1T) {
    __shared__ float embs[128];
    int h = blockIdx.x;                  // 256
    int tid = threadIdx.x;
    if (tid < 128) embs[tid] = 1.f + emb[tid];
    __syncthreads();
    int t2 = tid * 2;
    const ushort_t* base = fw1T + ((size_t)h << 16) + t2;
    float as0 = 0.f, as1 = 0.f, ae0 = 0.f, ae1 = 0.f;
#pragma unroll 4
    for (int e = 0; e < 128; ++e) {
        uint v = *(const uint*)(base + (size_t)e * 512);
        float v0 = bf2f((ushort_t)(v & 0xffff));
        float v1 = bf2f((ushort_t)(v >> 16));
        float w = embs[e];
        as0 += v0; as1 += v1;
        ae0 += w * v0; ae1 += w * v1;
    }
    F1T[(size_t)h * 512 + t2] = as0;
    F1T[(size_t)h * 512 + t2 + 1] = as1;
    F1T[131072 + (size_t)h * 512 + t2] = ae0;
    F1T[131072 + (size_t)h * 512 + t2 + 1] = ae1;
}

// ---------------- K5: pack F1s/F1e: B1cat rows 768-1023 (F1e hi|hi|lo), F1sT_bf, p2v = tb2@F1s ----------------
__global__ __launch_bounds__(64) void k_pack_F(const float* __restrict__ F1sT, const float* __restrict__ F1eT,
                                               const float* __restrict__ tb2,
                                               ushort_t* __restrict__ B1cat, ushort_t* __restrict__ F1sT_bf,
                                               float* __restrict__ p2v) {
    int h = blockIdx.x;                   // 256
    int lane = threadIdx.x;
    int t = lane * 8;
    float p2 = 0.f;
    short8 shi, ehi, elo;
    for (int j = 0; j < 8; ++j) {
        float vs = F1sT[(size_t)h * 512 + t + j];
        float ve = F1eT[(size_t)h * 512 + t + j];
        p2 += tb2[t + j] * vs;
        shi[j] = (short)f2bf(vs);
        ushort_t hi = f2bf(ve);
        ehi[j] = (short)hi;
        elo[j] = (short)f2bf(ve - bf2f(hi));
    }
    *(short8*)(F1sT_bf + (size_t)h * 512 + t) = shi;
    size_t row = (size_t)(768 + h) * 1536;
    *(short8*)(B1cat + row + t) = ehi;
    *(short8*)(B1cat + row + 512 + t) = ehi;
    *(short8*)(B1cat + row + 1024 + t) = elo;
    for (int o = 32; o > 0; o >>= 1) p2 += __shfl_xor(p2, o);
    if (lane == 0) p2v[h] = p2;
}

// ---------------- generic 128x128-tile bf16 MFMA GEMM; A [M][K] lda, B [N][K] ldb ----------------
// EPI 0: M2T contiguous tile store via LDS staging (grid 1024)
// EPI 2: G1: s f32 / hl bf16(leaky+tb1) / h2c f32 split by n  (grid 32)
// EPI 4: P2T transposed bf16 store (grid 4)
// EPI 5: h2b = acc + p2v[n] + h2c (grid 8)
template<int EPI>
__global__ __launch_bounds__(256) void k_mfma(const ushort_t* __restrict__ A, const ushort_t* __restrict__ Bm,
                                              int lda, int ldb, int kIters, int nTiles,
                                              void* __restrict__ C0, void* __restrict__ C1,
                                              void* __restrict__ C2, const float* __restrict__ aux) {
    __shared__ ushort_t shmem[2 * 128 * 72];
    ushort_t* As = shmem;
    ushort_t* Bs = shmem + 128 * 72;
    int tid = threadIdx.x;
    int lane = tid & 63, wid = tid >> 6;
    int wr = wid >> 1, wc = wid & 1;
    int bid = blockIdx.x;
    int mt, nt;
    if (EPI == 0) {
        int xx = bid & 7, y = bid >> 3;
        mt = y & 3;
        nt = ((y >> 2) << 3) | xx;
    } else {
        nt = bid % nTiles;
        mt = bid / nTiles;
    }
    int m0 = mt * 128, n0 = nt * 128;
    f32x4 acc[4][4] = {};
    for (int kt = 0; kt < kIters; ++kt) {
        int kb = kt * 64;
        __syncthreads();
        {
            uint4 va[4], vb[4];
            for (int i = 0; i < 4; ++i) {
                int q = tid + i * 256;
                int row = q >> 3, kcc = (q & 7) << 3;
                va[i] = *(const uint4*)(A + (size_t)(m0 + row) * lda + kb + kcc);
                vb[i] = *(const uint4*)(Bm + (size_t)(n0 + row) * ldb + kb + kcc);
            }
            for (int i = 0; i < 4; ++i) {
                int q = tid + i * 256;
                int row = q >> 3, kcc = (q & 7) << 3;
                *(uint4*)&As[row * 72 + kcc] = va[i];
                *(uint4*)&Bs[row * 72 + kcc] = vb[i];
            }
        }
        __syncthreads();
        for (int ks = 0; ks < 2; ++ks) {
            short8 a[4], b[4];
            int kk = ks * 32 + (lane >> 4) * 8;
            for (int mi = 0; mi < 4; ++mi)
                a[mi] = *(const short8*)&As[(wr * 64 + mi * 16 + (lane & 15)) * 72 + kk];
            for (int ni = 0; ni < 4; ++ni)
                b[ni] = *(const short8*)&Bs[(wc * 64 + ni * 16 + (lane & 15)) * 72 + kk];
            for (int mi = 0; mi < 4; ++mi)
                for (int ni = 0; ni < 4; ++ni)
                    acc[mi][ni] = __builtin_amdgcn_mfma_f32_16x16x32_bf16(a[mi], b[ni], acc[mi][ni], 0, 0, 0);
        }
    }
    if (EPI == 0) {
        // stage C tile (128x128 bf16 = one contiguous 32KB chunk of M2T) in LDS, then linear copy
        __syncthreads();
        for (int mi = 0; mi < 4; ++mi) {
            int ml = wr * 64 + mi * 16 + ((lane >> 4) << 2);
            for (int ni = 0; ni < 4; ++ni) {
                int nl = wc * 64 + ni * 16 + (lane & 15);
                for (int r = 0; r < 4; ++r)
                    shmem[(ml + r) * 128 + nl] = f2bf(acc[mi][ni][r]);
            }
        }
        __syncthreads();
        short8* d8 = (short8*)((ushort_t*)C0 + ((size_t)(n0 >> 7) << 16) + (size_t)m0 * 128);
        const short8* s8 = (const short8*)shmem;
        for (int i = 0; i < 8; ++i) d8[tid + i * 256] = s8[tid + i * 256];
        return;
    }
    int mb0 = m0 + wr * 64 + ((lane >> 4) << 2);
    int nb0 = n0 + wc * 64 + (lane & 15);
    for (int mi = 0; mi < 4; ++mi) {
        for (int ni = 0; ni < 4; ++ni) {
            int mbase = mb0 + mi * 16;
            int n = nb0 + ni * 16;
            if (EPI == 2) {
                float* s = (float*)C0;
                ushort_t* hl = (ushort_t*)C1;
                float* h2c = (float*)C2;
                for (int r = 0; r < 4; ++r) {
                    int m = mbase + r;
                    float v = acc[mi][ni][r];
                    if (n < 512) s[(size_t)m * 512 + n] = v;
                    else if (n < 768) hl[(size_t)m * 256 + (n - 512)] = f2bf(leaky_(v + aux[n - 512]));
                    else h2c[(size_t)m * 256 + (n - 768)] = v;
                }
            } else if (EPI == 4) {
                ushort_t* P2T = (ushort_t*)C0;
                ushort4 o;
                o.x = f2bf(acc[mi][ni][0]);
                o.y = f2bf(acc[mi][ni][1]);
                o.z = f2bf(acc[mi][ni][2]);
                o.w = f2bf(acc[mi][ni][3]);
                *(ushort4*)(P2T + (size_t)n * 256 + mbase) = o;
            } else if (EPI == 5) {
                float* h2b = (float*)C0;
                const float* h2c = (const float*)C1;
                for (int r = 0; r < 4; ++r) {
                    int m = mbase + r;
                    h2b[(size_t)m * 256 + n] = acc[mi][ni][r] + aux[n] + h2c[(size_t)m * 256 + n];
                }
            }
        }
    }
}

// ---------------- GEMM1: h2 += Yp @ M2T^T  (M=512, N=256, K=65536) ----------------
// BM=128, BN=256 (full N), 512 thr (8 waves 2x4), split-K 64 chunks of 1024.
// XCD map: same-kchunk blocks land on the same XCD so the 512KB B-chunk is fetched once per XCD L2.
__global__ __launch_bounds__(512) void k_gemm1(const ushort_t* __restrict__ A, const ushort_t* __restrict__ Bm,
                                               float* __restrict__ h2) {
    __shared__ ushort_t shmem[(128 + 256) * 72];
    ushort_t* As = shmem;
    ushort_t* Bs = shmem + 128 * 72;
    int tid = threadIdx.x;
    int lane = tid & 63, wid = tid >> 6;
    int wr = wid >> 2, wc = wid & 3;          // 2 x 4 waves; per wave 64m x 64n
    int bid = blockIdx.x;                     // 256
    int x = bid & 7, j = bid >> 3;            // x: XCD, j: 0..31
    int kc = x * 8 + (j >> 2);                // 64 k-chunks
    int mt = j & 3;
    int m0 = mt * 128;
    size_t k0 = (size_t)kc * 1024;
    f32x4 acc[4][4] = {};
    for (int kt = 0; kt < 16; ++kt) {
        size_t kb = k0 + kt * 64;
        __syncthreads();
        {
            uint4 va[2], vb[4];
            for (int i = 0; i < 2; ++i) {
                int q = tid + i * 512;
                int row = q >> 3, kcc = (q & 7) << 3;
                va[i] = *(const uint4*)(A + (size_t)(m0 + row) * 65536 + kb + kcc);
            }
            for (int i = 0; i < 4; ++i) {
                int q = tid + i * 512;
                int row = q >> 3, kcc = (q & 7) << 3;
                vb[i] = *(const uint4*)(Bm + (size_t)row * 65536 + kb + kcc);
            }
            for (int i = 0; i < 2; ++i) {
                int q = tid + i * 512;
                *(uint4*)&As[(q >> 3) * 72 + ((q & 7) << 3)] = va[i];
            }
            for (int i = 0; i < 4; ++i) {
                int q = tid + i * 512;
                *(uint4*)&Bs[(q >> 3) * 72 + ((q & 7) << 3)] = vb[i];
            }
        }
        __syncthreads();
        for (int ks = 0; ks < 2; ++ks) {
            short8 a[4], b[4];
            int kk = ks * 32 + (lane >> 4) * 8;
            for (int mi = 0; mi < 4; ++mi)
                a[mi] = *(const short8*)&As[(wr * 64 + mi * 16 + (lane & 15)) * 72 + kk];
            for (int ni = 0; ni < 4; ++ni)
                b[ni] = *(const short8*)&Bs[(wc * 64 + ni * 16 + (lane & 15)) * 72 + kk];
            for (int mi = 0; mi < 4; ++mi)
                for (int ni = 0; ni < 4; ++ni)
                    acc[mi][ni] = __builtin_amdgcn_mfma_f32_16x16x32_bf16(a[mi], b[ni], acc[mi][ni], 0, 0, 0);
        }
    }
    int mb0 = m0 + wr * 64 + ((lane >> 4) << 2);
    int nb0 = wc * 64 + (lane & 15);
    for (int mi = 0; mi < 4; ++mi)
        for (int ni = 0; ni < 4; ++ni) {
            int mbase = mb0 + mi * 16;
            int n = nb0 + ni * 16;
            for (int r = 0; r < 4; ++r)
                atomicAdd(h2 + (size_t)(mbase + r) * 256 + n, acc[mi][ni][r]);
        }
}

// ---------------- K7: assemble Yp[bn][k*128+e]; one k per 16-lane group => 1KB contiguous wave stores ----------------
__global__ __launch_bounds__(256) void k_assemble_Y(const float* __restrict__ s,
                                                    const ushort_t* __restrict__ Atab, const ushort_t* __restrict__ Btab,
                                                    const float* __restrict__ bpkey,
                                                    ushort_t* __restrict__ Yp) {
    __shared__ float bp_s[256];
    __shared__ float sv_s[256];
    __shared__ ushort_t r_s[256];
    int bn = blockIdx.x >> 1;          // 1024 blocks
    int k0 = (blockIdx.x & 1) << 8;
    int tid = threadIdx.x;
    bp_s[tid] = bpkey[tid];
    __syncthreads();
    // phase A: per-k region lookup
    {
        float sv = s[(size_t)bn * 512 + k0 + tid];
        int lo = 0, hi = 256;
        while (lo < hi) { int mid = (lo + hi) >> 1; if (bp_s[mid] <= sv) lo = mid + 1; else hi = mid; }
        sv_s[tid] = sv;
        r_s[tid] = (ushort_t)lo;
    }
    __syncthreads();
    // phase B: 16 passes; 16 lanes per k, each lane 8 e's
    int e0 = (tid & 15) * 8;
    for (int pass = 0; pass < 16; ++pass) {
        int kk = pass * 16 + (tid >> 4);
        float sv = sv_s[kk];
        int r = r_s[kk];
        short8 a8 = *(const short8*)(Atab + r * 128 + e0);
        short8 b8 = *(const short8*)(Btab + r * 128 + e0);
        short8 o;
        for (int j = 0; j < 8; ++j) {
            float y = sv * bf2f((ushort_t)a8[j]) + bf2f((ushort_t)b8[j]);
            y = (y > LAMBDA_) ? (y - LAMBDA_) : ((y < -LAMBDA_) ? (y + LAMBDA_) : 0.f);
            o[j] = (short)f2bf(y);
        }
        *(short8*)(Yp + (size_t)bn * 65536 + (size_t)(k0 + kk) * 128 + e0) = o;
    }
}

// ---------------- K10: final ----------------
__global__ __launch_bounds__(128) void k_final(const float* __restrict__ h2, const float* __restrict__ h2b,
                                               const float* __restrict__ fb1,
                                               const float* __restrict__ fw2, const float* __restrict__ fb2,
                                               float* __restrict__ out) {
    __shared__ float a_s[256];
    int bn = blockIdx.x;
    int tid = threadIdx.x;
    for (int i = tid; i < 256; i += 128)
        a_s[i] = leaky_(h2[(size_t)bn * 256 + i] + h2b[(size_t)bn * 256 + i] + fb1[i]);
    __syncthreads();
    if (tid < 96) {
        float acc = fb2[tid];
        for (int hh = 0; hh < 256; ++hh)
            acc += a_s[hh] * fw2[hh * 96 + tid];
        int b = bn >> 6, n = bn & 63;
        out[(size_t)(b * 96 + tid) * 64 + n] = acc;
    }
}

extern "C" void kernel_launch(void* const* d_in, const int* in_sizes, int n_in,
                              void* d_out, int out_size, void* d_ws, size_t ws_size,
                              hipStream_t stream) {
    const float* x   = (const float*)d_in[0];
    const float* emb = (const float*)d_in[1];
    const float* w1  = (const float*)d_in[2];
    const float* b1  = (const float*)d_in[3];
    const float* w2  = (const float*)d_in[4];
    const float* b2  = (const float*)d_in[5];
    const float* tw1 = (const float*)d_in[6];
    const float* tb1 = (const float*)d_in[7];
    const float* tw2 = (const float*)d_in[8];
    const float* tb2 = (const float*)d_in[9];
    const float* fw1 = (const float*)d_in[10];
    const float* fb1 = (const float*)d_in[11];
    const float* fw2 = (const float*)d_in[12];
    const float* fb2 = (const float*)d_in[13];
    float* out = (float*)d_out;

    char* W = (char*)d_ws;
    size_t off = 0;
    auto take = [&](size_t bytes) { size_t r = off; off += (bytes + 255) & ~(size_t)255; return r; };
    ushort_t* Yp    = (ushort_t*)(W + take(67108864));       // [512][65536] bf16 (k'=k*128+e)
    ushort_t* fw1T  = Yp;                                    // alias: [32768 j''=h*128+e][512 t], dead before Yp
    ushort_t* M2T   = (ushort_t*)(W + take(33554432));       // [256 h][65536 k']
    ushort_t* A1cat = (ushort_t*)(W + take(512 * 1536 * 2));
    ushort_t* B1cat = (ushort_t*)(W + take(1024 * 1536 * 2));
    ushort_t* Wt    = (ushort_t*)(W + take(512 * 512 * 2));
    ushort_t* tw2bf = (ushort_t*)(W + take(256 * 512 * 2));
    float* F1T      = (float*)(W + take(2 * 256 * 512 * 4)); // [2][h][t]
    ushort_t* F1sbf = (ushort_t*)(W + take(256 * 512 * 2));
    float* sbuf     = (float*)(W + take(512 * 512 * 4));
    ushort_t* hlbuf = (ushort_t*)(W + take(512 * 256 * 2));
    float* h2c      = (float*)(W + take(512 * 256 * 4));
    ushort_t* P2T   = (ushort_t*)(W + take(256 * 256 * 2));
    float* p2v      = (float*)(W + take(256 * 4));
    ushort_t* Atab  = (ushort_t*)(W + take(257 * 128 * 2));
    ushort_t* Btab  = (ushort_t*)(W + take(257 * 128 * 2));
    float* bpkey    = (float*)(W + take(256 * 4));
    float* h2       = (float*)(W + take(512 * 256 * 4));
    float* h2b      = (float*)(W + take(512 * 256 * 4));
    (void)ws_size; (void)in_sizes; (void)n_in; (void)out_size;

    hipMemsetAsync(h2, 0, 512 * 256 * 4, stream);

    k_setup<<<3072, 256, 0, stream>>>(tw2, B1cat, Wt, tw2bf);
    k_pack_tw1<<<32, 256, 0, stream>>>(tw1, B1cat);
    k_transpose_x<<<256, 256, 0, stream>>>(x, A1cat);
    k_prep<<<1, 256, 0, stream>>>(emb, w1, b1, w2, b2, Atab, Btab, bpkey);
    k_transpose_fw1<<<4096, 256, 0, stream>>>(fw1, fw1T);
    k_reduce_F2<<<256, 256, 0, stream>>>(fw1T, emb, F1T);
    k_pack_F<<<256, 64, 0, stream>>>(F1T, F1T + 131072, tb2, B1cat, F1sbf, p2v);
    // G1: [s | hl | h2c] = xTcat @ B1cat^T   (M=512, N=1024, K=1536 hi/lo)
    k_mfma<2><<<32, 256, 0, stream>>>(A1cat, B1cat, 1536, 1536, 24, 8, sbuf, hlbuf, h2c, tb1);
    // GEMM0: M2T = Wt @ fw1T^T  (M=512 k, N=32768 j'', K=512 t)
    k_mfma<0><<<1024, 256, 0, stream>>>(Wt, fw1T, 512, 512, 8, 256, M2T, nullptr, nullptr, nullptr);
    // P2' = tw2 @ F1s  (M=256 h'', N=256 h', K=512 t) -> P2T
    k_mfma<4><<<4, 256, 0, stream>>>(tw2bf, F1sbf, 512, 512, 8, 2, P2T, nullptr, nullptr, nullptr);
    // Yp = softshrink tables applied to s
    k_assemble_Y<<<1024, 256, 0, stream>>>(sbuf, Atab, Btab, bpkey, Yp);
    // h2 = Yp @ M2T^T  (M=512, N=256, K=65536, split-K 64, atomics)
    k_gemm1<<<256, 512, 0, stream>>>(Yp, M2T, h2);
    // h2b = hl @ P2'^T + p2v + h2c  (M=512, N=256, K=256)
    k_mfma<5><<<8, 256, 0, stream>>>(hlbuf, P2T, 256, 256, 4, 2, h2b, h2c, nullptr, p2v);
    k_final<<<512, 128, 0, stream>>>(h2, h2b, fb1, fw2, fb2, out);
}